// Round 3
// baseline (432.403 us; speedup 1.0000x reference)
//
#include <hip/hip_runtime.h>

#define BATCH 8
#define SDIM 2048
#define KDIM 2048
#define NDIM 2048
#define BM 128
#define BN 128
#define BK 32
#define KTILES (KDIM / BK)

typedef __bf16 bf16_t;
typedef bf16_t bf16x8 __attribute__((ext_vector_type(8)));
typedef float f32x4 __attribute__((ext_vector_type(4)));
typedef float f32x8 __attribute__((ext_vector_type(8)));

__global__ __launch_bounds__(256, 2)
void bgemm_kernel(const float* __restrict__ A, const float* __restrict__ B,
                  float* __restrict__ O) {
    // A LDS: [k-octet][row][k%8] bf16 — b128 writes/reads stride-16B: zero-conflict (R1-proven).
    // B LDS: [k-octet][p(col)][k%8], p(c)=(c&~15)+((c>>1)&7)+(c&1)*8 — fragment
    // ds_read_b128 covers 256B/quarter-wave exactly (zero-conflict); writes 2-way (free).
    __shared__ alignas(16) bf16_t Asl[2][4 * 128 * 8];
    __shared__ alignas(16) bf16_t Bsl[2][4 * 128 * 8];

    const int tid = threadIdx.x;
    const int gid = blockIdx.x;
    const int batch = gid & 7;         // one batch per XCD
    const int t = gid >> 3;
    const int bm = (t >> 4) * BM;
    const int bn = (t & 15) * BN;

    float* Ob = O + (size_t)batch * SDIM * NDIM;

    const int lane = tid & 63;
    const int wid = tid >> 6;
    const int wr = wid >> 1;
    const int wc = wid & 1;
    const int lr = lane & 15;
    const int lq = lane >> 4;

    // A staging role: row r0, k-half h0 (16 f32 per thread)
    const int r0 = tid & 127;
    const int h0 = tid >> 7;
    // B staging role: k-octet ko, column pair (nc, nc+1)
    const int ko = tid >> 6;
    const int nc = (tid & 63) * 2;
    const int pb = (nc & 0x70) + (tid & 7);   // p(nc); p(nc+1) = pb+8

    const float* Aptr = A + (size_t)batch * SDIM * KDIM
                          + (size_t)(bm + r0) * KDIM + h0 * 16;
    const float* Bptr = B + (size_t)batch * KDIM * NDIM
                          + (size_t)(ko * 8) * NDIM + bn + nc;

    // two staging sets (ping-pong; all indices compile-time constant)
    f32x8 aS[2][2];
    f32x8 bS[2][2];

#define LOAD_TILE(P, KT) do {                                                  \
    const float* ap_ = Aptr + (size_t)(KT) * BK;                               \
    float4 t0_ = *reinterpret_cast<const float4*>(ap_);                        \
    float4 t1_ = *reinterpret_cast<const float4*>(ap_ + 4);                    \
    float4 t2_ = *reinterpret_cast<const float4*>(ap_ + 8);                    \
    float4 t3_ = *reinterpret_cast<const float4*>(ap_ + 12);                   \
    aS[P][0] = (f32x8){t0_.x, t0_.y, t0_.z, t0_.w, t1_.x, t1_.y, t1_.z, t1_.w};\
    aS[P][1] = (f32x8){t2_.x, t2_.y, t2_.z, t2_.w, t3_.x, t3_.y, t3_.z, t3_.w};\
    const float* bp_ = Bptr + (size_t)(KT) * BK * NDIM;                        \
    float2 u0_ = *reinterpret_cast<const float2*>(bp_ + 0 * (size_t)NDIM);     \
    float2 u1_ = *reinterpret_cast<const float2*>(bp_ + 1 * (size_t)NDIM);     \
    float2 u2_ = *reinterpret_cast<const float2*>(bp_ + 2 * (size_t)NDIM);     \
    float2 u3_ = *reinterpret_cast<const float2*>(bp_ + 3 * (size_t)NDIM);     \
    float2 u4_ = *reinterpret_cast<const float2*>(bp_ + 4 * (size_t)NDIM);     \
    float2 u5_ = *reinterpret_cast<const float2*>(bp_ + 5 * (size_t)NDIM);     \
    float2 u6_ = *reinterpret_cast<const float2*>(bp_ + 6 * (size_t)NDIM);     \
    float2 u7_ = *reinterpret_cast<const float2*>(bp_ + 7 * (size_t)NDIM);     \
    bS[P][0] = (f32x8){u0_.x, u1_.x, u2_.x, u3_.x, u4_.x, u5_.x, u6_.x, u7_.x};\
    bS[P][1] = (f32x8){u0_.y, u1_.y, u2_.y, u3_.y, u4_.y, u5_.y, u6_.y, u7_.y};\
} while (0)

#define CVT_STORE(P) do {                                                      \
    bf16x8 a0_ = __builtin_convertvector(aS[P][0], bf16x8);                    \
    bf16x8 a1_ = __builtin_convertvector(aS[P][1], bf16x8);                    \
    *reinterpret_cast<bf16x8*>(&Asl[P][((h0 * 2 + 0) * 128 + r0) * 8]) = a0_;  \
    *reinterpret_cast<bf16x8*>(&Asl[P][((h0 * 2 + 1) * 128 + r0) * 8]) = a1_;  \
    bf16x8 b0_ = __builtin_convertvector(bS[P][0], bf16x8);                    \
    bf16x8 b1_ = __builtin_convertvector(bS[P][1], bf16x8);                    \
    *reinterpret_cast<bf16x8*>(&Bsl[P][(ko * 128 + pb) * 8]) = b0_;            \
    *reinterpret_cast<bf16x8*>(&Bsl[P][(ko * 128 + pb + 8) * 8]) = b1_;        \
} while (0)

    f32x4 acc[4][4];
#pragma unroll
    for (int m = 0; m < 4; ++m)
#pragma unroll
        for (int n = 0; n < 4; ++n)
            acc[m][n] = (f32x4){0.f, 0.f, 0.f, 0.f};

    // prologue: tile0 -> LDS[0]; tile1 loads in flight
    LOAD_TILE(0, 0);
    CVT_STORE(0);
    LOAD_TILE(1, 1);
    __syncthreads();

    // step P computes tile KT (parity P) from LDS[P]:
    //   frag reads -> issue loads(KT+2) -> MFMA -> cvt_store(KT+1 -> LDS[P^1]) -> barrier
#define STEP(P, KT) do {                                                       \
    bf16x8 af_[4], bf_[4];                                                     \
    _Pragma("unroll")                                                          \
    for (int m = 0; m < 4; ++m)                                                \
        af_[m] = *reinterpret_cast<const bf16x8*>(                             \
            &Asl[P][(lq * 128 + wr * 64 + m * 16 + lr) * 8]);                  \
    _Pragma("unroll")                                                          \
    for (int n = 0; n < 4; ++n)                                                \
        bf_[n] = *reinterpret_cast<const bf16x8*>(                             \
            &Bsl[P][(lq * 128 + wc * 64 + n * 16 + (lr >> 1) + (lr & 1) * 8) * 8]); \
    if ((KT) + 2 < KTILES) LOAD_TILE(P, (KT) + 2);                             \
    _Pragma("unroll")                                                          \
    for (int m = 0; m < 4; ++m)                                                \
        _Pragma("unroll")                                                      \
        for (int n = 0; n < 4; ++n)                                            \
            acc[m][n] = __builtin_amdgcn_mfma_f32_16x16x32_bf16(               \
                af_[m], bf_[n], acc[m][n], 0, 0, 0);                           \
    if ((KT) + 1 < KTILES) CVT_STORE(P ^ 1);                                   \
    __syncthreads();                                                           \
} while (0)

    for (int kt = 0; kt < KTILES; kt += 2) {
        STEP(0, kt);
        STEP(1, kt + 1);
    }

    // epilogue: C/D layout col=lane&15, row=(lane>>4)*4+reg
#pragma unroll
    for (int m = 0; m < 4; ++m) {
        const int row0 = bm + wr * 64 + m * 16 + lq * 4;
#pragma unroll
        for (int n = 0; n < 4; ++n) {
            const int col = bn + wc * 64 + n * 16 + lr;
#pragma unroll
            for (int j = 0; j < 4; ++j)
                Ob[(size_t)(row0 + j) * NDIM + col] = acc[m][n][j];
        }
    }
#undef STEP
#undef CVT_STORE
#undef LOAD_TILE
}

extern "C" void kernel_launch(void* const* d_in, const int* in_sizes, int n_in,
                              void* d_out, int out_size, void* d_ws, size_t ws_size,
                              hipStream_t stream) {
    const float* a = (const float*)d_in[0];
    const float* b = (const float*)d_in[1];
    float* o = (float*)d_out;
    dim3 grid(BATCH * (SDIM / BM) * (NDIM / BN));  // 2048
    dim3 block(256);
    hipLaunchKernelGGL(bgemm_kernel, grid, block, 0, stream, a, b, o);
}

// Round 4
// 342.930 us; speedup vs baseline: 1.2609x; 1.2609x over previous
//
#include <hip/hip_runtime.h>

#define BATCH 8
#define SDIM 2048
#define KDIM 2048
#define NDIM 2048

typedef __bf16 bf16_t;
typedef bf16_t bf16x4 __attribute__((ext_vector_type(4)));
typedef bf16_t bf16x8 __attribute__((ext_vector_type(8)));
typedef float f32x4 __attribute__((ext_vector_type(4)));
typedef float f32x8 __attribute__((ext_vector_type(8)));
typedef unsigned short u16x8 __attribute__((ext_vector_type(8)));

__device__ __forceinline__ void gl_lds16(const void* g, void* l) {
    // async global->LDS DMA, 16B/lane; LDS dest = wave-uniform base + lane*16
    __builtin_amdgcn_global_load_lds(
        (__attribute__((address_space(1))) void*)g,
        (__attribute__((address_space(3))) void*)l,
        16, 0, 0);
}

// ---------------- Pass 1a: A fp32 -> bf16 (elementwise) ----------------
__global__ __launch_bounds__(256)
void cvtA_kernel(const float* __restrict__ A, bf16_t* __restrict__ Abf) {
    const size_t total8 = (size_t)BATCH * SDIM * KDIM / 8;   // 4194304
    const size_t stride = (size_t)gridDim.x * 256;
    for (size_t i = (size_t)blockIdx.x * 256 + threadIdx.x; i < total8; i += stride) {
        f32x8 v = *reinterpret_cast<const f32x8*>(A + i * 8);
        *reinterpret_cast<bf16x8*>(Abf + i * 8) = __builtin_convertvector(v, bf16x8);
    }
}

// ------------- Pass 1b: B fp32 [K][N] -> bf16 B^T [N][K] ----------------
__global__ __launch_bounds__(256)
void cvtBT_kernel(const float* __restrict__ B, bf16_t* __restrict__ Bt) {
    __shared__ alignas(16) bf16_t T[64][72];   // +8 pad: all LDS ops <=2-way
    const int gid = blockIdx.x;
    const int batch = gid & 7;                  // one batch per XCD
    const int tile = gid >> 3;                  // 0..1023
    const int k0g = (tile >> 5) * 64;
    const int n0g = (tile & 31) * 64;
    const float* Bb = B + (size_t)batch * KDIM * NDIM + (size_t)k0g * NDIM + n0g;
    bf16_t* Tb = Bt + (size_t)batch * NDIM * KDIM + (size_t)n0g * KDIM + k0g;

    const int t = threadIdx.x;
    // read a 4(k) x 4(n) micro-block, transpose in registers
    const int kq = t & 15;    // k0 = kq*4
    const int nq = t >> 4;    // n4 = nq*4
    f32x4 v[4];
#pragma unroll
    for (int r = 0; r < 4; ++r)
        v[r] = *reinterpret_cast<const f32x4*>(Bb + (size_t)(kq * 4 + r) * NDIM + nq * 4);
#pragma unroll
    for (int j = 0; j < 4; ++j) {
        bf16x4 w = {(bf16_t)v[0][j], (bf16_t)v[1][j], (bf16_t)v[2][j], (bf16_t)v[3][j]};
        *reinterpret_cast<bf16x4*>(&T[nq * 4 + j][kq * 4]) = w;   // k-contig 8B store
    }
    __syncthreads();
    // write out: row n, 16 k-contiguous bf16 per thread -> coalesced 64B lines
    const int n = t >> 2, kc = t & 3;
    bf16x8 o0 = *reinterpret_cast<const bf16x8*>(&T[n][kc * 16]);
    bf16x8 o1 = *reinterpret_cast<const bf16x8*>(&T[n][kc * 16 + 8]);
    *reinterpret_cast<bf16x8*>(Tb + (size_t)n * KDIM + kc * 16) = o0;
    *reinterpret_cast<bf16x8*>(Tb + (size_t)n * KDIM + kc * 16 + 8) = o1;
}

// ---------------- Pass 2: bf16 GEMM, m97 structure ----------------------
// LDS chunk layout: chunk(row,koct) = (row>>4)*64 + koct*16 + (row&15), 16B chunks.
// gload_lds writes linearly (lane l -> chunk base+l): per inst, 16 rows x 64B
// fully-coalesced global lines. Fragment read (fixed koct=lq, rows +lr) is
// 256B-contiguous per 16-lane group -> zero bank conflict.
__global__ __launch_bounds__(256, 4)
void bgemm_bf16(const bf16_t* __restrict__ A, const bf16_t* __restrict__ Bt,
                float* __restrict__ O) {
    __shared__ alignas(16) bf16_t Asl[2][4096];   // 8KB per buf (128 x 32)
    __shared__ alignas(16) bf16_t Bsl[2][4096];

    const int tid = threadIdx.x;
    const int gid = blockIdx.x;
    const int batch = gid & 7;          // one batch per XCD
    const int t = gid >> 3;
    const int bm = (t >> 4) * 128;
    const int bn = (t & 15) * 128;

    const int lane = tid & 63;
    const int wv = tid >> 6;
    const int wr = wv >> 1, wc = wv & 1;
    const int lr = lane & 15, lq = lane >> 4;

    const bf16_t* Ab = A + (size_t)batch * SDIM * KDIM;
    const bf16_t* Bb = Bt + (size_t)batch * NDIM * KDIM;
    float* Ob = O + (size_t)batch * SDIM * NDIM;

    // staging: inst i covers rows (i*4+wv)*16 + lr, k-octet lq
    const bf16_t* aS0 = Ab + (size_t)(bm + (0 + wv) * 16 + lr) * KDIM + lq * 8;
    const bf16_t* aS1 = Ab + (size_t)(bm + (4 + wv) * 16 + lr) * KDIM + lq * 8;
    const bf16_t* bS0 = Bb + (size_t)(bn + (0 + wv) * 16 + lr) * KDIM + lq * 8;
    const bf16_t* bS1 = Bb + (size_t)(bn + (4 + wv) * 16 + lr) * KDIM + lq * 8;

    auto stage = [&](int P, int kt) {
        const size_t ko = (size_t)kt * 32;
        gl_lds16(aS0 + ko, &Asl[P][wv * 512]);
        gl_lds16(aS1 + ko, &Asl[P][(4 + wv) * 512]);
        gl_lds16(bS0 + ko, &Bsl[P][wv * 512]);
        gl_lds16(bS1 + ko, &Bsl[P][(4 + wv) * 512]);
    };

    f32x4 acc[4][4];
#pragma unroll
    for (int m = 0; m < 4; ++m)
#pragma unroll
        for (int n = 0; n < 4; ++n)
            acc[m][n] = (f32x4){0.f, 0.f, 0.f, 0.f};

    stage(0, 0);
    __syncthreads();

    int bufp = 0;
    for (int kt = 0; kt < KDIM / 32; ++kt) {
        if (kt + 1 < KDIM / 32) stage(bufp ^ 1, kt + 1);
        bf16x8 af[4], bfv[4];
#pragma unroll
        for (int m = 0; m < 4; ++m)
            af[m] = *reinterpret_cast<const bf16x8*>(
                &Asl[bufp][((wr * 4 + m) * 64 + lq * 16 + lr) * 8]);
#pragma unroll
        for (int n = 0; n < 4; ++n)
            bfv[n] = *reinterpret_cast<const bf16x8*>(
                &Bsl[bufp][((wc * 4 + n) * 64 + lq * 16 + lr) * 8]);
#pragma unroll
        for (int m = 0; m < 4; ++m)
#pragma unroll
            for (int n = 0; n < 4; ++n)
                acc[m][n] = __builtin_amdgcn_mfma_f32_16x16x32_bf16(
                    af[m], bfv[n], acc[m][n], 0, 0, 0);
        __syncthreads();
        bufp ^= 1;
    }

    // epilogue: C/D layout col=lane&15, row=(lane>>4)*4+reg (R1-verified)
#pragma unroll
    for (int m = 0; m < 4; ++m) {
        const int row0 = bm + wr * 64 + m * 16 + lq * 4;
#pragma unroll
        for (int n = 0; n < 4; ++n) {
            const int col = bn + wc * 64 + n * 16 + lr;
#pragma unroll
            for (int j = 0; j < 4; ++j)
                Ob[(size_t)(row0 + j) * NDIM + col] = acc[m][n][j];
        }
    }
}

// ---------------- Fallback: R1 fused kernel (proven, 444us) -------------
__device__ __forceinline__ unsigned short f2bf(float f) {
    unsigned int u = __builtin_bit_cast(unsigned int, f);
    u += 0x7fffu + ((u >> 16) & 1u);
    return (unsigned short)(u >> 16);
}

__global__ __launch_bounds__(256, 2)
void bgemm_fused(const float* __restrict__ A, const float* __restrict__ B,
                 float* __restrict__ O) {
    __shared__ alignas(16) unsigned short Asl[2][4 * 128 * 8];
    __shared__ alignas(16) unsigned short Bsl[2][4 * 128 * 8];
    const int tid = threadIdx.x;
    const int gid = blockIdx.x;
    const int batch = gid & 7;
    const int t = gid >> 3;
    const int bm = (t >> 4) * 128;
    const int bn = (t & 15) * 128;
    const float* Ab = A + (size_t)batch * SDIM * KDIM;
    const float* Bb = B + (size_t)batch * KDIM * NDIM;
    float* Ob = O + (size_t)batch * SDIM * NDIM;
    const int lane = tid & 63;
    const int wid = tid >> 6;
    const int wr = wid >> 1, wc = wid & 1;
    const int lr = lane & 15, lq = lane >> 4;
    const int r0 = tid & 127, h0 = tid >> 7;
    u16x8 areg[2], breg[2];
    f32x4 acc[4][4];
#pragma unroll
    for (int m = 0; m < 4; ++m)
#pragma unroll
        for (int n = 0; n < 4; ++n) acc[m][n] = (f32x4){0.f, 0.f, 0.f, 0.f};
    auto stage_regs = [&](int kt) {
        const int k0 = kt * 32;
        const float* ap = Ab + (size_t)(bm + r0) * KDIM + k0 + h0 * 16;
        float4 a0 = *reinterpret_cast<const float4*>(ap + 0);
        float4 a1 = *reinterpret_cast<const float4*>(ap + 4);
        float4 a2 = *reinterpret_cast<const float4*>(ap + 8);
        float4 a3 = *reinterpret_cast<const float4*>(ap + 12);
        u16x8 u;
        u[0]=f2bf(a0.x);u[1]=f2bf(a0.y);u[2]=f2bf(a0.z);u[3]=f2bf(a0.w);
        u[4]=f2bf(a1.x);u[5]=f2bf(a1.y);u[6]=f2bf(a1.z);u[7]=f2bf(a1.w);
        areg[0]=u;
        u[0]=f2bf(a2.x);u[1]=f2bf(a2.y);u[2]=f2bf(a2.z);u[3]=f2bf(a2.w);
        u[4]=f2bf(a3.x);u[5]=f2bf(a3.y);u[6]=f2bf(a3.z);u[7]=f2bf(a3.w);
        areg[1]=u;
        const float* bp = Bb + (size_t)(k0 + h0 * 16) * NDIM + bn + r0;
        float f[16];
#pragma unroll
        for (int j = 0; j < 16; ++j) f[j] = bp[(size_t)j * NDIM];
        u16x8 v;
#pragma unroll
        for (int j = 0; j < 8; ++j) v[j] = f2bf(f[j]);
        breg[0] = v;
#pragma unroll
        for (int j = 0; j < 8; ++j) v[j] = f2bf(f[8 + j]);
        breg[1] = v;
    };
    auto regs_to_lds = [&](int b) {
#pragma unroll
        for (int o = 0; o < 2; ++o) {
            *reinterpret_cast<u16x8*>(&Asl[b][((h0*2+o)*128 + r0)*8]) = areg[o];
            *reinterpret_cast<u16x8*>(&Bsl[b][((h0*2+o)*128 + r0)*8]) = breg[o];
        }
    };
    stage_regs(0);
    regs_to_lds(0);
    int buf = 0;
    for (int kt = 0; kt < KDIM / 32; ++kt) {
        if (kt + 1 < KDIM / 32) stage_regs(kt + 1);
        __syncthreads();
        bf16x8 af[4], bfv[4];
#pragma unroll
        for (int m = 0; m < 4; ++m)
            af[m] = *reinterpret_cast<const bf16x8*>(&Asl[buf][(lq*128 + wr*64 + m*16 + lr)*8]);
#pragma unroll
        for (int n = 0; n < 4; ++n)
            bfv[n] = *reinterpret_cast<const bf16x8*>(&Bsl[buf][(lq*128 + wc*64 + n*16 + lr)*8]);
#pragma unroll
        for (int m = 0; m < 4; ++m)
#pragma unroll
            for (int n = 0; n < 4; ++n)
                acc[m][n] = __builtin_amdgcn_mfma_f32_16x16x32_bf16(af[m], bfv[n], acc[m][n], 0, 0, 0);
        if (kt + 1 < KDIM / 32) regs_to_lds(buf ^ 1);
        buf ^= 1;
    }
#pragma unroll
    for (int m = 0; m < 4; ++m) {
        const int row0 = bm + wr * 64 + m * 16 + lq * 4;
#pragma unroll
        for (int n = 0; n < 4; ++n) {
            const int col = bn + wc * 64 + n * 16 + lr;
#pragma unroll
            for (int j = 0; j < 4; ++j)
                Ob[(size_t)(row0 + j) * NDIM + col] = acc[m][n][j];
        }
    }
}

extern "C" void kernel_launch(void* const* d_in, const int* in_sizes, int n_in,
                              void* d_out, int out_size, void* d_ws, size_t ws_size,
                              hipStream_t stream) {
    const float* a = (const float*)d_in[0];
    const float* b = (const float*)d_in[1];
    float* o = (float*)d_out;
    const size_t half = (size_t)BATCH * SDIM * KDIM * sizeof(bf16_t);  // 64 MiB
    if (ws_size >= 2 * half) {
        bf16_t* Abf = (bf16_t*)d_ws;
        bf16_t* Bt = (bf16_t*)((char*)d_ws + half);
        hipLaunchKernelGGL(cvtA_kernel, dim3(4096), dim3(256), 0, stream, a, Abf);
        hipLaunchKernelGGL(cvtBT_kernel, dim3(8192), dim3(256), 0, stream, b, Bt);
        hipLaunchKernelGGL(bgemm_bf16, dim3(2048), dim3(256), 0, stream, Abf, Bt, o);
    } else {
        hipLaunchKernelGGL(bgemm_fused, dim3(2048), dim3(256), 0, stream, a, b, o);
    }
}

// Round 5
// 244.525 us; speedup vs baseline: 1.7683x; 1.4024x over previous
//
#include <hip/hip_runtime.h>

#define BATCH 8
#define SDIM 2048
#define KDIM 2048
#define NDIM 2048

typedef __bf16 bf16_t;
typedef bf16_t bf16x4 __attribute__((ext_vector_type(4)));
typedef bf16_t bf16x8 __attribute__((ext_vector_type(8)));
typedef float f32x4 __attribute__((ext_vector_type(4)));
typedef float f32x8 __attribute__((ext_vector_type(8)));
typedef unsigned short u16x8 __attribute__((ext_vector_type(8)));

__device__ __forceinline__ void gl_lds16(const void* g, void* l) {
    // async global->LDS DMA, 16B/lane; LDS dest = wave-uniform base + lane*16
    __builtin_amdgcn_global_load_lds(
        (__attribute__((address_space(1))) void*)g,
        (__attribute__((address_space(3))) void*)l,
        16, 0, 0);
}

// ---------------- Pass 1a: A fp32 -> bf16 (elementwise) ----------------
__global__ __launch_bounds__(256)
void cvtA_kernel(const float* __restrict__ A, bf16_t* __restrict__ Abf) {
    const size_t total8 = (size_t)BATCH * SDIM * KDIM / 8;
    const size_t stride = (size_t)gridDim.x * 256;
    for (size_t i = (size_t)blockIdx.x * 256 + threadIdx.x; i < total8; i += stride) {
        f32x8 v = *reinterpret_cast<const f32x8*>(A + i * 8);
        *reinterpret_cast<bf16x8*>(Abf + i * 8) = __builtin_convertvector(v, bf16x8);
    }
}

// ------------- Pass 1b: B fp32 [K][N] -> bf16 B^T [N][K] ----------------
__global__ __launch_bounds__(256)
void cvtBT_kernel(const float* __restrict__ B, bf16_t* __restrict__ Bt) {
    __shared__ alignas(16) bf16_t T[64][72];
    const int gid = blockIdx.x;
    const int batch = gid & 7;
    const int tile = gid >> 3;
    const int k0g = (tile >> 5) * 64;
    const int n0g = (tile & 31) * 64;
    const float* Bb = B + (size_t)batch * KDIM * NDIM + (size_t)k0g * NDIM + n0g;
    bf16_t* Tb = Bt + (size_t)batch * NDIM * KDIM + (size_t)n0g * KDIM + k0g;

    const int t = threadIdx.x;
    const int kq = t & 15;
    const int nq = t >> 4;
    f32x4 v[4];
#pragma unroll
    for (int r = 0; r < 4; ++r)
        v[r] = *reinterpret_cast<const f32x4*>(Bb + (size_t)(kq * 4 + r) * NDIM + nq * 4);
#pragma unroll
    for (int j = 0; j < 4; ++j) {
        bf16x4 w = {(bf16_t)v[0][j], (bf16_t)v[1][j], (bf16_t)v[2][j], (bf16_t)v[3][j]};
        *reinterpret_cast<bf16x4*>(&T[nq * 4 + j][kq * 4]) = w;
    }
    __syncthreads();
    const int n = t >> 2, kc = t & 3;
    bf16x8 o0 = *reinterpret_cast<const bf16x8*>(&T[n][kc * 16]);
    bf16x8 o1 = *reinterpret_cast<const bf16x8*>(&T[n][kc * 16 + 8]);
    *reinterpret_cast<bf16x8*>(Tb + (size_t)n * KDIM + kc * 16) = o0;
    *reinterpret_cast<bf16x8*>(Tb + (size_t)n * KDIM + kc * 16 + 8) = o1;
}

// ---------------- Pass 2: 256x256 8-phase counted-vmcnt GEMM ------------
// 8 waves (2M x 4N), BK=32, 4-deep K-tile LDS ring (4 x 32KB = 128KB).
// KT m lives in buffer (m&3). Iteration t computes KT 4t..4t+3 (8 phases,
// one (KT, m-half) per phase, 16 MFMA each). Stages: p0/p1 -> KT 4t+3 (b3),
// p2/p3 -> 4t+4 (b0), p4/p5 -> 4t+5 (b1), p6/p7 -> 4t+6 (b2). Each stage
// issues >=1 phase after its slot's last-read barrier (WAR-safe); vmcnt(4)
// at end of p3/p7 (+barrier) guarantees landing 2+ phases before first read.
// LDS per buffer per matrix: [rowOct][kQ][16 rows][16B] - DMA-linear
// (byte(lane)=lane*16) and fragment reads 256B-contiguous (0-conflict).
#define VM4 asm volatile("s_waitcnt vmcnt(4)" ::: "memory")
#define VM0 asm volatile("s_waitcnt vmcnt(0)" ::: "memory")
#define NOOP ((void)0)

__global__ __launch_bounds__(512, 2)
void bgemm_8ph(const bf16_t* __restrict__ A, const bf16_t* __restrict__ Bt,
               float* __restrict__ O) {
    __shared__ alignas(16) bf16_t lds[65536];   // 128 KiB

    const int tid = threadIdx.x;
    const int gid = blockIdx.x;
    const int batch = gid & 7;          // one batch per XCD
    const int t = gid >> 3;
    const int bm = (t >> 3) * 256;
    const int bn = (t & 7) * 256;

    const int lane = tid & 63;
    const int wid = tid >> 6;           // 0..7
    const int wr = wid >> 2;            // 0..1 (128-row half)
    const int wc = wid & 3;             // 0..3 (64-col quarter)
    const int lr = lane & 15;
    const int lq = lane >> 4;

    const bf16_t* Ab = A + (size_t)batch * SDIM * KDIM;
    const bf16_t* Bb = Bt + (size_t)batch * NDIM * KDIM;
    float* Ob = O + (size_t)batch * SDIM * NDIM;

    // staging sources: wave w covers rows w*32..w*32+31 (2 insts of 16 rows)
    const bf16_t* aSrc0 = Ab + (size_t)(bm + wid * 32 + lr) * KDIM + lq * 8;
    const bf16_t* aSrc1 = aSrc0 + (size_t)16 * KDIM;
    const bf16_t* bSrc0 = Bb + (size_t)(bn + wid * 32 + lr) * KDIM + lq * 8;
    const bf16_t* bSrc1 = bSrc0 + (size_t)16 * KDIM;

    const int aDst0 = (wid * 2) * 512;       // LDS elem offset of rowOct 2w
    const int aDst1 = (wid * 2 + 1) * 512;
    const int rdA = lq * 128 + lr * 8;       // + (wr*8+mh*4+m)*512 + buf*16384
    const int rdB = 8192 + lq * 128 + lr * 8;

#define STAGE_A(BUF_, KT_) do { \
    gl_lds16(aSrc0 + (size_t)(KT_) * 32, &lds[(BUF_) * 16384 + aDst0]); \
    gl_lds16(aSrc1 + (size_t)(KT_) * 32, &lds[(BUF_) * 16384 + aDst1]); \
} while (0)
#define STAGE_B(BUF_, KT_) do { \
    gl_lds16(bSrc0 + (size_t)(KT_) * 32, &lds[(BUF_) * 16384 + 8192 + aDst0]); \
    gl_lds16(bSrc1 + (size_t)(KT_) * 32, &lds[(BUF_) * 16384 + 8192 + aDst1]); \
} while (0)

    f32x4 acc[8][4];
#pragma unroll
    for (int m = 0; m < 8; ++m)
#pragma unroll
        for (int n = 0; n < 4; ++n)
            acc[m][n] = (f32x4){0.f, 0.f, 0.f, 0.f};

    bf16x8 bfrag[4];   // B-frags held across the two phases of a K-tile

#define PHASE(BUF_, MH_, STAGE_STMT, WAIT_STMT) do { \
    bf16x8 af_[4]; \
    _Pragma("unroll") \
    for (int m_ = 0; m_ < 4; ++m_) \
        af_[m_] = *reinterpret_cast<const bf16x8*>( \
            &lds[(BUF_) * 16384 + (wr * 8 + (MH_) * 4 + m_) * 512 + rdA]); \
    if ((MH_) == 0) { \
        _Pragma("unroll") \
        for (int n_ = 0; n_ < 4; ++n_) \
            bfrag[n_] = *reinterpret_cast<const bf16x8*>( \
                &lds[(BUF_) * 16384 + (wc * 4 + n_) * 512 + rdB]); \
    } \
    STAGE_STMT; \
    __builtin_amdgcn_s_barrier(); \
    __builtin_amdgcn_s_setprio(1); \
    _Pragma("unroll") \
    for (int m_ = 0; m_ < 4; ++m_) \
        _Pragma("unroll") \
        for (int n_ = 0; n_ < 4; ++n_) \
            acc[(MH_) * 4 + m_][n_] = __builtin_amdgcn_mfma_f32_16x16x32_bf16( \
                af_[m_], bfrag[n_], acc[(MH_) * 4 + m_][n_], 0, 0, 0); \
    __builtin_amdgcn_s_setprio(0); \
    WAIT_STMT; \
    __builtin_amdgcn_s_barrier(); \
} while (0)

    // prologue: KT0->b0, KT1->b1, KT2->b2; KT0/KT1 landed, KT2 in flight
    STAGE_A(0, 0); STAGE_B(0, 0);
    STAGE_A(1, 1); STAGE_B(1, 1);
    STAGE_A(2, 2); STAGE_B(2, 2);
    VM4;
    __builtin_amdgcn_s_barrier();

#pragma unroll 1
    for (int it = 0; it < 15; ++it) {
        const int k4 = it * 4;
        PHASE(0, 0, STAGE_A(3, k4 + 3), NOOP);
        PHASE(0, 1, STAGE_B(3, k4 + 3), NOOP);
        PHASE(1, 0, STAGE_A(0, k4 + 4), NOOP);
        PHASE(1, 1, STAGE_B(0, k4 + 4), VM4);
        PHASE(2, 0, STAGE_A(1, k4 + 5), NOOP);
        PHASE(2, 1, STAGE_B(1, k4 + 5), NOOP);
        PHASE(3, 0, STAGE_A(2, k4 + 6), NOOP);
        PHASE(3, 1, STAGE_B(2, k4 + 6), VM4);
    }
    // peeled last iteration: KT 60..63 (only KT63 still to stage)
    PHASE(0, 0, STAGE_A(3, 63), NOOP);
    PHASE(0, 1, STAGE_B(3, 63), NOOP);
    PHASE(1, 0, NOOP, NOOP);
    PHASE(1, 1, NOOP, VM0);
    PHASE(2, 0, NOOP, NOOP);
    PHASE(2, 1, NOOP, NOOP);
    PHASE(3, 0, NOOP, NOOP);
    PHASE(3, 1, NOOP, NOOP);

    // epilogue: C/D layout col=lane&15, row=(lane>>4)*4+reg (R1-verified)
#pragma unroll
    for (int m = 0; m < 8; ++m) {
        const int row0 = bm + wr * 128 + m * 16 + lq * 4;
#pragma unroll
        for (int n = 0; n < 4; ++n) {
            const int col = bn + wc * 64 + n * 16 + lr;
#pragma unroll
            for (int j = 0; j < 4; ++j)
                Ob[(size_t)(row0 + j) * NDIM + col] = acc[m][n][j];
        }
    }
#undef PHASE
#undef STAGE_A
#undef STAGE_B
}

// ---------------- Fallback: R1 fused kernel (proven) --------------------
__device__ __forceinline__ unsigned short f2bf(float f) {
    unsigned int u = __builtin_bit_cast(unsigned int, f);
    u += 0x7fffu + ((u >> 16) & 1u);
    return (unsigned short)(u >> 16);
}

__global__ __launch_bounds__(256, 2)
void bgemm_fused(const float* __restrict__ A, const float* __restrict__ B,
                 float* __restrict__ O) {
    __shared__ alignas(16) unsigned short Asl[2][4 * 128 * 8];
    __shared__ alignas(16) unsigned short Bsl[2][4 * 128 * 8];
    const int tid = threadIdx.x;
    const int gid = blockIdx.x;
    const int batch = gid & 7;
    const int t = gid >> 3;
    const int bm = (t >> 4) * 128;
    const int bn = (t & 15) * 128;
    const float* Ab = A + (size_t)batch * SDIM * KDIM;
    const float* Bb = B + (size_t)batch * KDIM * NDIM;
    float* Ob = O + (size_t)batch * SDIM * NDIM;
    const int lane = tid & 63;
    const int wid = tid >> 6;
    const int wr = wid >> 1, wc = wid & 1;
    const int lr = lane & 15, lq = lane >> 4;
    const int r0 = tid & 127, h0 = tid >> 7;
    u16x8 areg[2], breg[2];
    f32x4 acc[4][4];
#pragma unroll
    for (int m = 0; m < 4; ++m)
#pragma unroll
        for (int n = 0; n < 4; ++n) acc[m][n] = (f32x4){0.f, 0.f, 0.f, 0.f};
    auto stage_regs = [&](int kt) {
        const int k0 = kt * 32;
        const float* ap = Ab + (size_t)(bm + r0) * KDIM + k0 + h0 * 16;
        float4 a0 = *reinterpret_cast<const float4*>(ap + 0);
        float4 a1 = *reinterpret_cast<const float4*>(ap + 4);
        float4 a2 = *reinterpret_cast<const float4*>(ap + 8);
        float4 a3 = *reinterpret_cast<const float4*>(ap + 12);
        u16x8 u;
        u[0]=f2bf(a0.x);u[1]=f2bf(a0.y);u[2]=f2bf(a0.z);u[3]=f2bf(a0.w);
        u[4]=f2bf(a1.x);u[5]=f2bf(a1.y);u[6]=f2bf(a1.z);u[7]=f2bf(a1.w);
        areg[0]=u;
        u[0]=f2bf(a2.x);u[1]=f2bf(a2.y);u[2]=f2bf(a2.z);u[3]=f2bf(a2.w);
        u[4]=f2bf(a3.x);u[5]=f2bf(a3.y);u[6]=f2bf(a3.z);u[7]=f2bf(a3.w);
        areg[1]=u;
        const float* bp = Bb + (size_t)(k0 + h0 * 16) * NDIM + bn + r0;
        float f[16];
#pragma unroll
        for (int j = 0; j < 16; ++j) f[j] = bp[(size_t)j * NDIM];
        u16x8 v;
#pragma unroll
        for (int j = 0; j < 8; ++j) v[j] = f2bf(f[j]);
        breg[0] = v;
#pragma unroll
        for (int j = 0; j < 8; ++j) v[j] = f2bf(f[8 + j]);
        breg[1] = v;
    };
    auto regs_to_lds = [&](int b) {
#pragma unroll
        for (int o = 0; o < 2; ++o) {
            *reinterpret_cast<u16x8*>(&Asl[b][((h0*2+o)*128 + r0)*8]) = areg[o];
            *reinterpret_cast<u16x8*>(&Bsl[b][((h0*2+o)*128 + r0)*8]) = breg[o];
        }
    };
    stage_regs(0);
    regs_to_lds(0);
    int buf = 0;
    for (int kt = 0; kt < KDIM / 32; ++kt) {
        if (kt + 1 < KDIM / 32) stage_regs(kt + 1);
        __syncthreads();
        bf16x8 af[4], bfv[4];
#pragma unroll
        for (int m = 0; m < 4; ++m)
            af[m] = *reinterpret_cast<const bf16x8*>(&Asl[buf][(lq*128 + wr*64 + m*16 + lr)*8]);
#pragma unroll
        for (int n = 0; n < 4; ++n)
            bfv[n] = *reinterpret_cast<const bf16x8*>(&Bsl[buf][(lq*128 + wc*64 + n*16 + lr)*8]);
#pragma unroll
        for (int m = 0; m < 4; ++m)
#pragma unroll
            for (int n = 0; n < 4; ++n)
                acc[m][n] = __builtin_amdgcn_mfma_f32_16x16x32_bf16(af[m], bfv[n], acc[m][n], 0, 0, 0);
        if (kt + 1 < KDIM / 32) regs_to_lds(buf ^ 1);
        buf ^= 1;
    }
#pragma unroll
    for (int m = 0; m < 4; ++m) {
        const int row0 = bm + wr * 64 + m * 16 + lq * 4;
#pragma unroll
        for (int n = 0; n < 4; ++n) {
            const int col = bn + wc * 64 + n * 16 + lr;
#pragma unroll
            for (int j = 0; j < 4; ++j)
                Ob[(size_t)(row0 + j) * NDIM + col] = acc[m][n][j];
        }
    }
}

extern "C" void kernel_launch(void* const* d_in, const int* in_sizes, int n_in,
                              void* d_out, int out_size, void* d_ws, size_t ws_size,
                              hipStream_t stream) {
    const float* a = (const float*)d_in[0];
    const float* b = (const float*)d_in[1];
    float* o = (float*)d_out;
    const size_t half = (size_t)BATCH * SDIM * KDIM * sizeof(bf16_t);  // 64 MiB
    if (ws_size >= 2 * half) {
        bf16_t* Abf = (bf16_t*)d_ws;
        bf16_t* Bt = (bf16_t*)((char*)d_ws + half);
        hipLaunchKernelGGL(cvtA_kernel, dim3(4096), dim3(256), 0, stream, a, Abf);
        hipLaunchKernelGGL(cvtBT_kernel, dim3(8192), dim3(256), 0, stream, b, Bt);
        hipLaunchKernelGGL(bgemm_8ph, dim3(512), dim3(512), 0, stream, Abf, Bt, o);
    } else {
        hipLaunchKernelGGL(bgemm_fused, dim3(2048), dim3(256), 0, stream, a, b, o);
    }
}